// Round 6
// baseline (279.833 us; speedup 1.0000x reference)
//
#include <hip/hip_runtime.h>

// TopKRouter: N=32768 tokens, D=2048, E=64, K=2.
// R6 = R2's scalar-w datapath (w via s_load, e-outer/m-inner KB=32, VALU at
// floor count) + R5's 8-wave occupancy (512 thr, 4 waves/SIMD). x staged in
// LDS (double-buffered); w read directly from global through the scalar path.

#define NTOK 32768
#define DDIM 2048
#define NEXP 64
#define TTILE 64          // tokens per block
#define KB 32             // k-chunk
#define NCH (DDIM / KB)   // 64
#define XS_STRIDE 36      // 32 + 4 pad
#define LG_STRIDE 68      // 64 + 4 pad for logit tail
#define BUFSZ (TTILE * XS_STRIDE)

#define OFF_IDX 0
#define OFF_W 65536
#define OFF_CNT 131072
#define OFF_OVF 131136
#define OFF_ZL 131137
#define OFF_ENT 131138
#define OFF_VAR 131139
#define OFF_CONF 131140

struct RouterWS {
  unsigned int counts[NEXP];
  double z_sum;
  double ent_sum;
};

__global__ __launch_bounds__(512, 4) void router_main(
    const float* __restrict__ x, const float* __restrict__ w,
    float* __restrict__ out, RouterWS* __restrict__ ws) {
  // x double-buffer only; logit tile (64*68 <= 2*BUFSZ) aliases it after the
  // last barrier.
  __shared__ float smem[2 * BUFSZ];
  __shared__ unsigned int hist[NEXP];

  const int tid = threadIdx.x;                              // 0..511
  const int lane = tid & 63;                                // token-in-block
  const int wv = __builtin_amdgcn_readfirstlane(tid >> 6);  // expert group 0..7

  const float* xg = x + (size_t)blockIdx.x * TTILE * DDIM;

  // x staging map: 512 float4 per chunk, 1 per thread
  const int srow = tid >> 3;
  const int scol = (tid & 7) * 4;

  // Prefetch chunk 0.
  float4 rx = *(const float4*)(xg + (size_t)srow * DDIM + scol);
  *(float4*)&smem[srow * XS_STRIDE + scol] = rx;

  float acc[8];
#pragma unroll
  for (int e = 0; e < 8; ++e) acc[e] = 0.f;

  const float* wbase = w + (size_t)wv * 8 * DDIM;  // uniform -> scalar path

  __syncthreads();

  for (int c = 0; c < NCH; ++c) {
    const int cb = (c & 1) * BUFSZ;
    const int nb = ((c + 1) & 1) * BUFSZ;

    if (c + 1 < NCH) {  // issue next x chunk; returns under FMAs
      int k0 = (c + 1) * KB;
      rx = *(const float4*)(xg + (size_t)srow * DDIM + k0 + scol);
    }

    // my token's 32 x-values -> VGPRs (8 ds_read_b128, reused by 8 experts)
    float4 xr4[8];
#pragma unroll
    for (int m = 0; m < 8; ++m)
      xr4[m] = *(const float4*)&smem[cb + lane * XS_STRIDE + 4 * m];

    const float* wc = wbase + c * KB;
#pragma unroll
    for (int e = 0; e < 8; ++e) {
      const float4* we = (const float4*)(wc + (size_t)e * DDIM);  // s_load
      float a = acc[e];
#pragma unroll
      for (int m = 0; m < 8; ++m) {
        float4 wq = we[m];
        a = fmaf(xr4[m].x, wq.x, a);
        a = fmaf(xr4[m].y, wq.y, a);
        a = fmaf(xr4[m].z, wq.z, a);
        a = fmaf(xr4[m].w, wq.w, a);
      }
      acc[e] = a;
    }

    if (c + 1 < NCH) {  // load returned by now; stage next buffer
      *(float4*)&smem[nb + srow * XS_STRIDE + scol] = rx;
    }
    __syncthreads();
  }

  // logits -> smem front as lg[token][expert], stride 68
#pragma unroll
  for (int m = 0; m < 2; ++m)
    *(float4*)&smem[lane * LG_STRIDE + wv * 8 + 4 * m] = *(float4*)&acc[4 * m];
  if (tid < NEXP) hist[tid] = 0;
  __syncthreads();

  if (tid < NEXP) {  // wave 0: one token per lane, serial over 64 experts
    const int t = tid;
    const float* L = &smem[t * LG_STRIDE];

    float m1 = L[0];
    int i1 = 0;
    for (int e = 1; e < NEXP; ++e) {
      float v = L[e];
      if (v > m1) { m1 = v; i1 = e; }  // strict > keeps lowest index on ties
    }
    float m2 = -3.4e38f;
    int i2 = 0;
    for (int e = 0; e < NEXP; ++e) {
      if (e == i1) continue;
      float v = L[e];
      if (v > m2) { m2 = v; i2 = e; }
    }

    float s = 0.f;
    for (int e = 0; e < NEXP; ++e) s += expf(L[e] - m1);
    float p1 = expf(L[i1] - m1) / s;
    float p2 = expf(L[i2] - m1) / s;
    float wsum = p1 + p2 + 1e-8f;
    float w1 = p1 / wsum;
    float w2 = p2 / wsum;

    float ent = 0.f;
    for (int e = 0; e < NEXP; ++e) {
      float p = expf(L[e] - m1) / s;
      ent -= p * logf(p + 1e-10f);
    }
    float lse = m1 + logf(s);

    size_t gt = (size_t)blockIdx.x * TTILE + t;
    out[OFF_IDX + gt * 2 + 0] = (float)i1;
    out[OFF_IDX + gt * 2 + 1] = (float)i2;
    out[OFF_W + gt * 2 + 0] = w1;
    out[OFF_W + gt * 2 + 1] = w2;
    out[OFF_CONF + gt] = fmaxf(w1, w2);

    atomicAdd(&hist[i1], 1u);
    atomicAdd(&hist[i2], 1u);

    float zv = lse, ev = ent;
#pragma unroll
    for (int o = 32; o > 0; o >>= 1) {
      zv += __shfl_down(zv, o);
      ev += __shfl_down(ev, o);
    }
    if (t == 0) {
      atomicAdd(&ws->z_sum, (double)zv);
      atomicAdd(&ws->ent_sum, (double)ev);
    }
  }
  __syncthreads();
  if (tid < NEXP) atomicAdd(&ws->counts[tid], hist[tid]);
}

__global__ void router_final(float* __restrict__ out, RouterWS* __restrict__ ws) {
  int e = threadIdx.x;  // 64 threads
  float c = (float)ws->counts[e];
  out[OFF_CNT + e] = c;
  float over = fmaxf(c - 1280.f, 0.f);   // capacity = int(1.25*32768/64*2)
  float ld = c / 65536.f - (1.f / 64.f);
  float so = over, sv = ld * ld;
#pragma unroll
  for (int o = 32; o > 0; o >>= 1) {
    so += __shfl_down(so, o);
    sv += __shfl_down(sv, o);
  }
  if (e == 0) {
    out[OFF_OVF] = so / 32768.f * 100.f;
    out[OFF_VAR] = sv / 64.f;
    out[OFF_ZL] = (float)(ws->z_sum / 32768.0 * 0.01);
    out[OFF_ENT] = (float)(ws->ent_sum / 32768.0);
  }
}

extern "C" void kernel_launch(void* const* d_in, const int* in_sizes, int n_in,
                              void* d_out, int out_size, void* d_ws, size_t ws_size,
                              hipStream_t stream) {
  const float* x = (const float*)d_in[0];   // hidden_states [4,8192,2048] f32
  const float* w = (const float*)d_in[1];   // gate_weight [64,2048] f32
  float* out = (float*)d_out;
  RouterWS* ws = (RouterWS*)d_ws;

  (void)hipMemsetAsync(d_ws, 0, sizeof(RouterWS), stream);
  hipLaunchKernelGGL(router_main, dim3(NTOK / TTILE), dim3(512), 0, stream,
                     x, w, out, ws);
  hipLaunchKernelGGL(router_final, dim3(1), dim3(64), 0, stream, out, ws);
}

// Round 7
// 236.155 us; speedup vs baseline: 1.1850x; 1.1850x over previous
//
#include <hip/hip_runtime.h>

// TopKRouter: N=32768 tokens, D=2048, E=64, K=2.
// R7: 2 tokens/lane (TTILE=128, grid=256) doubles w-reuse per s_load and FMA
// run-length per barrier; x staged via async global_load_lds (vmcnt-tracked,
// decoupled from the lgkm chain); XOR-involution swizzle (source col ^ row&7,
// read col ^ row&7) with linear LDS dest. w stays on the scalar path.

#define NTOK 32768
#define DDIM 2048
#define NEXP 64
#define TTILE 128          // tokens per block
#define KB 32              // k-chunk (floats)
#define NCH (DDIM / KB)    // 64
#define STG 4096           // floats per stage buffer (128 rows * 32)
#define LG_STRIDE 68       // 64 + 4 pad for logit tail

#define OFF_IDX 0
#define OFF_W 65536
#define OFF_CNT 131072
#define OFF_OVF 131136
#define OFF_ZL 131137
#define OFF_ENT 131138
#define OFF_VAR 131139
#define OFF_CONF 131140

struct RouterWS {
  unsigned int counts[NEXP];
  double z_sum;
  double ent_sum;
};

typedef __attribute__((address_space(1))) void v1_t;
typedef __attribute__((address_space(3))) void v3_t;

__device__ __forceinline__ void cp16(const float* g, float* l) {
  // async global->LDS, 16B per lane; dest must be wave-uniform base + lane*16
  __builtin_amdgcn_global_load_lds((v1_t*)g, (v3_t*)l, 16, 0, 0);
}

__global__ __launch_bounds__(512, 2) void router_main(
    const float* __restrict__ x, const float* __restrict__ w,
    float* __restrict__ out, RouterWS* __restrict__ ws) {
  // [0,STG) stage buf0 | [STG,2*STG) buf1 ; logit tile [0,128*68) aliases both
  // after the final K-loop barrier. 8704 floats = 34 KB.
  __shared__ float smem[TTILE * LG_STRIDE];
  __shared__ unsigned int hist[NEXP];

  const int tid = threadIdx.x;                              // 0..511
  const int L = tid & 63;                                   // lane = token row
  const int wv = __builtin_amdgcn_readfirstlane(tid >> 6);  // expert group 0..7
  const int s = L & 7;                                      // read swizzle key

  const float* xg = x + (size_t)blockIdx.x * TTILE * DDIM;

  // staging: thread tid owns LDS slots tid and tid+512 (rows sr and sr+64)
  const int sr = tid >> 3;                   // 0..63
  const int sq = tid & 7;                    // float4 col slot
  const int scol = 4 * (sq ^ (sr & 7));      // swizzled source float col

  // precomputed swizzled read offsets (floats), compile-time indexed
  int moff[8];
#pragma unroll
  for (int m = 0; m < 8; ++m) moff[m] = 4 * (m ^ s);
  const int rb0 = 32 * L;                    // token L row base (floats)
  const int rb1 = 2048 + 32 * L;             // token L+64 row base

  // issue chunk 0 into buf0
  cp16(xg + (size_t)sr * DDIM + scol, &smem[tid * 4]);
  cp16(xg + (size_t)(sr + 64) * DDIM + scol, &smem[2048 + tid * 4]);

  float acc0[8], acc1[8];
#pragma unroll
  for (int e = 0; e < 8; ++e) { acc0[e] = 0.f; acc1[e] = 0.f; }

  const float* wbase = w + (size_t)wv * 8 * DDIM;  // uniform -> scalar path

  __syncthreads();  // compiler drains vmcnt(0) before s_barrier

#define STEP(C, CB, NB)                                                        \
  {                                                                            \
    const int c_ = (C);                                                        \
    if (c_ + 1 < NCH) { /* async-issue next chunk; drains at end barrier */    \
      int k0 = (c_ + 1) * KB;                                                  \
      cp16(xg + (size_t)sr * DDIM + k0 + scol, &smem[(NB) + tid * 4]);         \
      cp16(xg + (size_t)(sr + 64) * DDIM + k0 + scol,                          \
           &smem[(NB) + 2048 + tid * 4]);                                      \
    }                                                                          \
    float4 xr0[8], xr1[8];                                                     \
    _Pragma("unroll") for (int m = 0; m < 8; ++m) {                            \
      xr0[m] = *(const float4*)&smem[(CB) + rb0 + moff[m]];                    \
      xr1[m] = *(const float4*)&smem[(CB) + rb1 + moff[m]];                    \
    }                                                                          \
    const float* wc = wbase + c_ * KB;                                         \
    _Pragma("unroll") for (int e = 0; e < 8; ++e) {                            \
      const float4* we = (const float4*)(wc + (size_t)e * DDIM);               \
      float a0 = acc0[e], a1 = acc1[e];                                        \
      _Pragma("unroll") for (int m = 0; m < 8; ++m) {                          \
        float4 wq = we[m];                                                     \
        a0 = fmaf(xr0[m].x, wq.x, a0);                                         \
        a0 = fmaf(xr0[m].y, wq.y, a0);                                         \
        a0 = fmaf(xr0[m].z, wq.z, a0);                                         \
        a0 = fmaf(xr0[m].w, wq.w, a0);                                         \
        a1 = fmaf(xr1[m].x, wq.x, a1);                                         \
        a1 = fmaf(xr1[m].y, wq.y, a1);                                         \
        a1 = fmaf(xr1[m].z, wq.z, a1);                                         \
        a1 = fmaf(xr1[m].w, wq.w, a1);                                         \
      }                                                                        \
      acc0[e] = a0;                                                            \
      acc1[e] = a1;                                                            \
    }                                                                          \
    __syncthreads();                                                           \
  }

  for (int cc = 0; cc < NCH; cc += 2) {
    STEP(cc, 0, STG);       // compile-time buffer bases -> ds offsets fold
    STEP(cc + 1, STG, 0);
  }
#undef STEP

  // logits -> lg[token][expert] (stride 68); scalar stores keep accs in regs
#pragma unroll
  for (int m = 0; m < 8; ++m) {
    smem[L * LG_STRIDE + wv * 8 + m] = acc0[m];
    smem[(L + 64) * LG_STRIDE + wv * 8 + m] = acc1[m];
  }
  if (tid < NEXP) hist[tid] = 0;
  __syncthreads();

  if (tid < 128) {  // waves 0-1: one token per lane, serial over 64 experts
    const int t = tid;
    const float* Lg = &smem[t * LG_STRIDE];

    float m1 = Lg[0];
    int i1 = 0;
    for (int e = 1; e < NEXP; ++e) {
      float v = Lg[e];
      if (v > m1) { m1 = v; i1 = e; }  // strict > keeps lowest index on ties
    }
    float m2 = -3.4e38f;
    int i2 = 0;
    for (int e = 0; e < NEXP; ++e) {
      if (e == i1) continue;
      float v = Lg[e];
      if (v > m2) { m2 = v; i2 = e; }
    }

    float sden = 0.f;
    for (int e = 0; e < NEXP; ++e) sden += expf(Lg[e] - m1);
    float p1 = expf(Lg[i1] - m1) / sden;
    float p2 = expf(Lg[i2] - m1) / sden;
    float wsum = p1 + p2 + 1e-8f;
    float w1 = p1 / wsum;
    float w2 = p2 / wsum;

    float ent = 0.f;
    for (int e = 0; e < NEXP; ++e) {
      float p = expf(Lg[e] - m1) / sden;
      ent -= p * logf(p + 1e-10f);
    }
    float lse = m1 + logf(sden);

    size_t gt = (size_t)blockIdx.x * TTILE + t;
    out[OFF_IDX + gt * 2 + 0] = (float)i1;
    out[OFF_IDX + gt * 2 + 1] = (float)i2;
    out[OFF_W + gt * 2 + 0] = w1;
    out[OFF_W + gt * 2 + 1] = w2;
    out[OFF_CONF + gt] = fmaxf(w1, w2);

    atomicAdd(&hist[i1], 1u);
    atomicAdd(&hist[i2], 1u);

    float zv = lse, ev = ent;
#pragma unroll
    for (int o = 32; o > 0; o >>= 1) {
      zv += __shfl_down(zv, o);
      ev += __shfl_down(ev, o);
    }
    if ((tid & 63) == 0) {  // one atomic per participating wave
      atomicAdd(&ws->z_sum, (double)zv);
      atomicAdd(&ws->ent_sum, (double)ev);
    }
  }
  __syncthreads();
  if (tid < NEXP) atomicAdd(&ws->counts[tid], hist[tid]);
}

__global__ void router_final(float* __restrict__ out, RouterWS* __restrict__ ws) {
  int e = threadIdx.x;  // 64 threads
  float c = (float)ws->counts[e];
  out[OFF_CNT + e] = c;
  float over = fmaxf(c - 1280.f, 0.f);   // capacity = int(1.25*32768/64*2)
  float ld = c / 65536.f - (1.f / 64.f);
  float so = over, sv = ld * ld;
#pragma unroll
  for (int o = 32; o > 0; o >>= 1) {
    so += __shfl_down(so, o);
    sv += __shfl_down(sv, o);
  }
  if (e == 0) {
    out[OFF_OVF] = so / 32768.f * 100.f;
    out[OFF_VAR] = sv / 64.f;
    out[OFF_ZL] = (float)(ws->z_sum / 32768.0 * 0.01);
    out[OFF_ENT] = (float)(ws->ent_sum / 32768.0);
  }
}

extern "C" void kernel_launch(void* const* d_in, const int* in_sizes, int n_in,
                              void* d_out, int out_size, void* d_ws, size_t ws_size,
                              hipStream_t stream) {
  const float* x = (const float*)d_in[0];   // hidden_states [4,8192,2048] f32
  const float* w = (const float*)d_in[1];   // gate_weight [64,2048] f32
  float* out = (float*)d_out;
  RouterWS* ws = (RouterWS*)d_ws;

  (void)hipMemsetAsync(d_ws, 0, sizeof(RouterWS), stream);
  hipLaunchKernelGGL(router_main, dim3(NTOK / TTILE), dim3(512), 0, stream,
                     x, w, out, ws);
  hipLaunchKernelGGL(router_final, dim3(1), dim3(64), 0, stream, out, ws);
}